// Round 5
// baseline (227.108 us; speedup 1.0000x reference)
//
#include <hip/hip_runtime.h>
#include <math.h>

static constexpr int B_ = 4;
static constexpr int L_ = 1024;
static constexpr int S_ = 1024;
static constexpr int DMODEL = 512;
static constexpr int NH = 8;
static constexpr int DH = 64;
static constexpr int NBH = 32;   // B_*NH

typedef __attribute__((ext_vector_type(8))) short s8;      // 8 bf16 (4 VGPRs)
typedef __attribute__((ext_vector_type(4))) float floatx4; // MFMA accumulator

__device__ __forceinline__ short f2bf(float f) {           // RNE f32->bf16
  unsigned u = __float_as_uint(f);
  return (short)((u + 0x7fffu + ((u >> 16) & 1u)) >> 16);
}
__device__ __forceinline__ float bf2f(short s) {
  return __uint_as_float(((unsigned)(unsigned short)s) << 16);
}

// ---------------------------------------------------------------------------
// Convert queries/keys/values (f32) -> contiguous bf16 segments in ws.
// ---------------------------------------------------------------------------
__global__ __launch_bounds__(256)
void cvt_inputs_kernel(const float* __restrict__ q, const float* __restrict__ k,
                       const float* __restrict__ v, short* __restrict__ dst) {
  const int i = blockIdx.x * 256 + threadIdx.x;          // 0..786431
  const int arr = i >> 18;                               // 0..2 (uniform per block)
  const int off = (i & 262143) << 3;
  const float* src = (arr == 0) ? q : (arr == 1) ? k : v;
  const float4 f0 = *(const float4*)(src + off);
  const float4 f1 = *(const float4*)(src + off + 4);
  s8 o;
  o[0] = f2bf(f0.x); o[1] = f2bf(f0.y); o[2] = f2bf(f0.z); o[3] = f2bf(f0.w);
  o[4] = f2bf(f1.x); o[5] = f2bf(f1.y); o[6] = f2bf(f1.z); o[7] = f2bf(f1.w);
  *(s8*)(dst + (size_t)arr * 2097152 + off) = o;
}

// ---------------------------------------------------------------------------
// Transpose + cvt the 4 weight matrices: W (512x512 f32, [k][n]) -> WT bf16 [n][k]
// ---------------------------------------------------------------------------
__global__ __launch_bounds__(256)
void wtrans_kernel(const float* __restrict__ Wq, const float* __restrict__ Wk,
                   const float* __restrict__ Wv, const float* __restrict__ Wo,
                   short* __restrict__ WT) {
  __shared__ float t[32][33];
  const int z = blockIdx.z;
  const float* W = (z == 0) ? Wq : (z == 1) ? Wk : (z == 2) ? Wv : Wo;
  short* dst = WT + (size_t)z * 262144;
  const int k0 = blockIdx.y * 32, n0 = blockIdx.x * 32;
  const int row = threadIdx.x >> 3;          // 0..31
  const int c4 = (threadIdx.x & 7) << 2;     // 0,4,..28
  const float4 f = *(const float4*)(W + (size_t)(k0 + row) * 512 + n0 + c4);
  t[row][c4 + 0] = f.x; t[row][c4 + 1] = f.y; t[row][c4 + 2] = f.z; t[row][c4 + 3] = f.w;
  __syncthreads();
#pragma unroll
  for (int j = 0; j < 4; ++j)
    dst[(size_t)(n0 + row) * 512 + k0 + c4 + j] = f2bf(t[c4 + j][row]);
}

// ---------------------------------------------------------------------------
// MFMA projection GEMM: C = A(M x K, bf16 row-major) @ WT^T (WT is N x K bf16).
// MODE 0: store bf16 (B,H,L,D); blockIdx.z selects {q,k} (A/WT/C offset by z)
// MODE 2: f32 row-major
// MODE 3: dual store bf16 vT (B,H,D,S) at C and vS (B,H,S,D) at C2
// ---------------------------------------------------------------------------
template<int MODE>
__global__ __launch_bounds__(256)
void proj_mfma_kernel(const short* __restrict__ A, const short* __restrict__ WT,
                      void* __restrict__ C, short* __restrict__ C2, int K) {
  const int z = blockIdx.z;
  A  += (size_t)z * 2097152;
  WT += (size_t)z * 262144;
  const int tid = threadIdx.x;
  const int lane = tid & 63, w = tid >> 6;
  const int wm = w >> 1, wn = w & 1;
  const int m0 = blockIdx.y * 64, n0 = blockIdx.x * 64;
  const int kl = (lane >> 4) << 3;            // 0,8,16,24
  const int rA = m0 + wm * 32 + (lane & 15);
  const int rB = n0 + wn * 32 + (lane & 15);
  const short* pA = A + (size_t)rA * K + kl;
  const short* pB = WT + (size_t)rB * K + kl;
  const size_t f16K = (size_t)16 * K;
  floatx4 acc00 = {0,0,0,0}, acc01 = {0,0,0,0}, acc10 = {0,0,0,0}, acc11 = {0,0,0,0};
  for (int k = 0; k < K; k += 32) {
    const s8 a0 = *(const s8*)(pA + k);
    const s8 a1 = *(const s8*)(pA + f16K + k);
    const s8 b0 = *(const s8*)(pB + k);
    const s8 b1 = *(const s8*)(pB + f16K + k);
    acc00 = __builtin_amdgcn_mfma_f32_16x16x32_bf16(a0, b0, acc00, 0, 0, 0);
    acc01 = __builtin_amdgcn_mfma_f32_16x16x32_bf16(a0, b1, acc01, 0, 0, 0);
    acc10 = __builtin_amdgcn_mfma_f32_16x16x32_bf16(a1, b0, acc10, 0, 0, 0);
    acc11 = __builtin_amdgcn_mfma_f32_16x16x32_bf16(a1, b1, acc11, 0, 0, 0);
  }
  const int crow = (lane >> 4) << 2;          // 0,4,8,12
  const int ccol = lane & 15;
#pragma unroll
  for (int fm = 0; fm < 2; ++fm)
#pragma unroll
    for (int fn = 0; fn < 2; ++fn) {
      const floatx4 acc = (fm == 0) ? ((fn == 0) ? acc00 : acc01)
                                    : ((fn == 0) ? acc10 : acc11);
      const int col = n0 + wn * 32 + fn * 16 + ccol;
#pragma unroll
      for (int r = 0; r < 4; ++r) {
        const int row = m0 + wm * 32 + fm * 16 + crow + r;
        if (MODE == 0) {
          const int b = row >> 10, l = row & 1023, h = col >> 6, d = col & 63;
          ((short*)C)[(size_t)z * 2097152 +
                      ((size_t)((b * NH + h) * L_ + l)) * DH + d] = f2bf(acc[r]);
        } else if (MODE == 3) {
          const int b = row >> 10, s = row & 1023, h = col >> 6, d = col & 63;
          const short val = f2bf(acc[r]);
          ((short*)C)[((size_t)((b * NH + h) * DH + d)) * S_ + s] = val;   // vT
          C2[((size_t)((b * NH + h) * S_ + s)) * DH + d] = val;            // vS
        } else {
          ((float*)C)[(size_t)row * DMODEL + col] = acc[r];
        }
      }
    }
}

// ---------------------------------------------------------------------------
// pm_fused: path_mean WITHOUT materialized scores.
//   pm[i][j] = (1/32) sum_bh Sc[bh][i][m1] * Sc[bh][m2][j],
//   m1=(2i+j)/3, m2=(i+2j)/3.
// Per 32x32 output tile (i0,j0): m1 in [c0,c0+31], m2 in [r0,r0+31] where
// c0=(2i0+j0)/3, r0=(i0+2j0)/3 (exact: (x+93)/3 = x/3+31).
// Each wave recomputes, per bh, the two needed 32x32 score tiles from
// L2-resident q/k via MFMA into wave-private LDS, gathers, accumulates.
// Waves process bh = w, w+4, ..., w+28; cross-wave reduce at the end.
// ---------------------------------------------------------------------------
__global__ __launch_bounds__(256)
void pm_fused_kernel(const short* __restrict__ qbf, const short* __restrict__ kbf,
                     float* __restrict__ pm) {
  __shared__ __align__(16) float SA[4][32][33];
  __shared__ __align__(16) float SB[4][32][33];

  const int orig = blockIdx.x;
  const int wgid = (orig & 7) * 128 + (orig >> 3);     // bijective XCD swizzle
  const int i0 = (wgid >> 5) << 5;
  const int j0 = (wgid & 31) << 5;
  const int c0 = (2 * i0 + j0) / 3;
  const int r0 = (i0 + 2 * j0) / 3;

  const int tid = threadIdx.x;
  const int lane = tid & 63, w = tid >> 6;
  const int frow = lane & 15;            // MFMA A/B fragment row
  const int kl = (lane >> 4) << 3;       // fragment k offset 0,8,16,24
  const int ti = lane & 31;              // owned pm row within tile
  const int tjb = (lane >> 5) << 4;      // owned pm col base (0 or 16)

  int aoff[16], boff[16];
#pragma unroll
  for (int u = 0; u < 16; ++u) {
    const int gi = i0 + ti, gj = j0 + tjb + u;
    const int m1 = (2 * gi + gj) / 3;
    const int m2 = (gi + 2 * gj) / 3;
    aoff[u] = ti * 33 + (m1 - c0);
    boff[u] = (m2 - r0) * 33 + (tjb + u);
  }
  float acc[16];
#pragma unroll
  for (int u = 0; u < 16; ++u) acc[u] = 0.f;

  float* SAw = &SA[w][0][0];
  float* SBw = &SB[w][0][0];
  const int crow = (lane >> 4) << 2;
  const int ccol = lane & 15;

  for (int bh = w; bh < NBH; bh += 4) {
    const short* Qb = qbf + (size_t)bh * L_ * DH;
    const short* Kb = kbf + (size_t)bh * S_ * DH;
#pragma unroll
    for (int t = 0; t < 2; ++t) {
      const int rb = t ? r0 : i0;        // Q-row window
      const int cb = t ? j0 : c0;        // K-row window
      const short* pQ = Qb + (size_t)(rb + frow) * DH + kl;
      const short* pK = Kb + (size_t)(cb + frow) * DH + kl;
      floatx4 a00 = {0,0,0,0}, a01 = {0,0,0,0}, a10 = {0,0,0,0}, a11 = {0,0,0,0};
#pragma unroll
      for (int ks = 0; ks < DH; ks += 32) {
        const s8 qa = *(const s8*)(pQ + ks);
        const s8 qb2 = *(const s8*)(pQ + 16 * DH + ks);
        const s8 ka = *(const s8*)(pK + ks);
        const s8 kb2 = *(const s8*)(pK + 16 * DH + ks);
        a00 = __builtin_amdgcn_mfma_f32_16x16x32_bf16(qa,  ka,  a00, 0, 0, 0);
        a01 = __builtin_amdgcn_mfma_f32_16x16x32_bf16(qa,  kb2, a01, 0, 0, 0);
        a10 = __builtin_amdgcn_mfma_f32_16x16x32_bf16(qb2, ka,  a10, 0, 0, 0);
        a11 = __builtin_amdgcn_mfma_f32_16x16x32_bf16(qb2, kb2, a11, 0, 0, 0);
      }
      float* dst = t ? SBw : SAw;
#pragma unroll
      for (int fm = 0; fm < 2; ++fm)
#pragma unroll
        for (int fn = 0; fn < 2; ++fn) {
          const floatx4 a = (fm == 0) ? ((fn == 0) ? a00 : a01)
                                      : ((fn == 0) ? a10 : a11);
#pragma unroll
          for (int r = 0; r < 4; ++r)
            dst[(fm * 16 + crow + r) * 33 + fn * 16 + ccol] = a[r] * 0.125f;
        }
    }
    // wave-private LDS: compiler orders ds_write -> ds_read within the wave
#pragma unroll
    for (int u = 0; u < 16; ++u)
      acc[u] = fmaf(SAw[aoff[u]], SBw[boff[u]], acc[u]);
  }

  // cross-wave reduction: overlay partials (pitch 36) on SA/SB after a barrier
  __syncthreads();
  float* P = &SA[0][0][0];               // SA+SB flat: 8448 floats available
#pragma unroll
  for (int u4 = 0; u4 < 4; ++u4) {
    float4 v4 = make_float4(acc[u4 * 4], acc[u4 * 4 + 1],
                            acc[u4 * 4 + 2], acc[u4 * 4 + 3]);
    *(float4*)&P[w * 1152 + ti * 36 + tjb + u4 * 4] = v4;
  }
  __syncthreads();
  const int ti2 = tid >> 3;              // 0..31
  const int tj2 = (tid & 7) << 2;        // 0..28
  float4 ssum = make_float4(0.f, 0.f, 0.f, 0.f);
#pragma unroll
  for (int w2 = 0; w2 < 4; ++w2) {
    const float4 v = *(const float4*)&P[w2 * 1152 + ti2 * 36 + tj2];
    ssum.x += v.x; ssum.y += v.y; ssum.z += v.z; ssum.w += v.w;
  }
  ssum.x *= (1.f / 32.f); ssum.y *= (1.f / 32.f);
  ssum.z *= (1.f / 32.f); ssum.w *= (1.f / 32.f);
  *(float4*)&pm[(size_t)(i0 + ti2) * S_ + j0 + tj2] = ssum;
}

// ---------------------------------------------------------------------------
// pm_stats: per row i of pm (far positions only, |i-j|>3):
//   pmmax[i], pmsum[i] = sum_far exp(pm-pmmax), E[i,j] = bf16(exp(..)) (0 on band)
// ---------------------------------------------------------------------------
__global__ __launch_bounds__(256)
void pm_stats_kernel(const float* __restrict__ pm, short* __restrict__ E,
                     float* __restrict__ pmmax, float* __restrict__ pmsum) {
  const int wid = threadIdx.x >> 6, lane = threadIdx.x & 63;
  const int i = blockIdx.x * 4 + wid;
  const float* row = pm + (size_t)i * S_;
  const int j0 = lane << 4;
  float v[16];
#pragma unroll
  for (int c = 0; c < 4; ++c) {
    const float4 f = *(const float4*)(row + j0 + c * 4);
    v[c * 4 + 0] = f.x; v[c * 4 + 1] = f.y; v[c * 4 + 2] = f.z; v[c * 4 + 3] = f.w;
  }
  float mx = -1e30f;
#pragma unroll
  for (int u = 0; u < 16; ++u) {
    const int d = i - (j0 + u);
    const bool far = (d > 3) || (d < -3);
    if (far) mx = fmaxf(mx, v[u]);
  }
#pragma unroll
  for (int off = 32; off >= 1; off >>= 1) mx = fmaxf(mx, __shfl_xor(mx, off));
  float sum = 0.f;
  short e[16];
#pragma unroll
  for (int u = 0; u < 16; ++u) {
    const int d = i - (j0 + u);
    const bool far = (d > 3) || (d < -3);
    const float ev = far ? __expf(v[u] - mx) : 0.f;
    sum += ev;
    e[u] = f2bf(ev);
  }
#pragma unroll
  for (int off = 32; off >= 1; off >>= 1) sum += __shfl_xor(sum, off);
  s8 o0, o1;
#pragma unroll
  for (int u = 0; u < 8; ++u) { o0[u] = e[u]; o1[u] = e[8 + u]; }
  short* Erow = E + (size_t)i * S_ + j0;
  *(s8*)Erow = o0;
  *(s8*)(Erow + 8) = o1;
  if (lane == 0) { pmmax[i] = mx; pmsum[i] = sum; }
}

// ---------------------------------------------------------------------------
// attn_write: one wave per (bh,i). Band scores recomputed from q/k (no score
// buffer). Writes the full attn row: far = c*E[i,:], band = exp(s-m)/denom.
// Emits c and the band attn values for the EV epilogue.
// ---------------------------------------------------------------------------
__global__ __launch_bounds__(256)
void attn_write_kernel(float* __restrict__ attnOut, const short* __restrict__ E,
                       const float* __restrict__ pmmax, const float* __restrict__ pmsum,
                       const short* __restrict__ qbf, const short* __restrict__ kbf,
                       float* __restrict__ cvec, float* __restrict__ band) {
  const int wid = threadIdx.x >> 6, lane = threadIdx.x & 63;
  const int i = blockIdx.x * 4 + wid;
  const int bh = blockIdx.y;

  // band score s_u for lanes 0..6 (j = i-3+lane); others -1e30
  const int j_u = i - 3 + lane;
  float s_u = -1e30f;
  if (lane < 7 && j_u >= 0 && j_u < S_) {
    const short* qr = qbf + ((size_t)bh * L_ + i) * DH;
    const short* kr = kbf + ((size_t)bh * S_ + j_u) * DH;
    float d0 = 0.f;
#pragma unroll
    for (int c = 0; c < 8; ++c) {
      const s8 qv = *(const s8*)(qr + c * 8);
      const s8 kv = *(const s8*)(kr + c * 8);
#pragma unroll
      for (int e = 0; e < 8; ++e) d0 = fmaf(bf2f(qv[e]), bf2f(kv[e]), d0);
    }
    s_u = d0 * 0.125f;
  }

  float bm = s_u;
#pragma unroll
  for (int off = 32; off >= 1; off >>= 1) bm = fmaxf(bm, __shfl_xor(bm, off));
  const float pmx = pmmax[i];
  const float m = fmaxf(pmx, bm);
  const float bexp = __expf(s_u - m);          // 0 for invalid lanes
  float bsum = bexp;
#pragma unroll
  for (int off = 32; off >= 1; off >>= 1) bsum += __shfl_xor(bsum, off);
  const float cpm = __expf(pmx - m);
  const float inv = 1.f / (bsum + pmsum[i] * cpm);
  const float c = cpm * inv;

  if (lane == 0) cvec[bh * L_ + i] = c;
  if (lane < 8) band[((size_t)(bh * L_ + i)) << 3 | lane] = bexp * inv;

  float bb[7];
#pragma unroll
  for (int u = 0; u < 7; ++u) bb[u] = __shfl(bexp, u) * inv;

  // write the attn row: far = c * E, band from bb
  float* row = attnOut + ((size_t)bh * L_ + i) * S_;
  const short* Erow = E + (size_t)i * S_;
  const int j0 = lane << 4;
  const s8 e0 = *(const s8*)(Erow + j0);
  const s8 e1 = *(const s8*)(Erow + j0 + 8);
  float outv[16];
#pragma unroll
  for (int u = 0; u < 8; ++u) {
    outv[u]     = bf2f(e0[u]) * c;
    outv[8 + u] = bf2f(e1[u]) * c;
  }
#pragma unroll
  for (int t = 0; t < 16; ++t) {
    const int d = (j0 + t) - i;
    if (d >= -3 && d <= 3) outv[t] = bb[d + 3];
  }
#pragma unroll
  for (int c4 = 0; c4 < 4; ++c4)
    *(float4*)(row + j0 + c4 * 4) =
        make_float4(outv[c4 * 4], outv[c4 * 4 + 1], outv[c4 * 4 + 2], outv[c4 * 4 + 3]);
}

// ---------------------------------------------------------------------------
// EV GEMM + band epilogue: out1 = c*(E @ V_bh) + sum_band attn_band * V.
// Band V rows (70) staged in LDS to kill scattered global loads.
// ---------------------------------------------------------------------------
__global__ __launch_bounds__(256)
void ev_kernel(const short* __restrict__ E, const short* __restrict__ vT,
               const short* __restrict__ vS, const float* __restrict__ cvec,
               const float* __restrict__ band, short* __restrict__ out1) {
  __shared__ short Vb[70 * 64];
  const int tid = threadIdx.x;
  const int m0 = blockIdx.x * 64;
  const int bh = blockIdx.y;
  const int b = bh >> 3, h = bh & 7;

  for (int idx = tid; idx < 560; idx += 256) {
    const int rr = idx >> 3, c8 = (idx & 7) << 3;
    int j = m0 - 3 + rr; j = j < 0 ? 0 : (j > 1023 ? 1023 : j);
    *(s8*)&Vb[rr * 64 + c8] = *(const s8*)(vS + ((size_t)bh * S_ + j) * DH + c8);
  }
  __syncthreads();

  const int lane = tid & 63, w = tid >> 6;
  const int wm = w >> 1, wn = w & 1;
  const int kl = (lane >> 4) << 3;
  const short* pA = E + (size_t)(m0 + wm * 32 + (lane & 15)) * S_ + kl;
  const short* pB = vT + (size_t)bh * DH * S_ + (size_t)(wn * 32 + (lane & 15)) * S_ + kl;
  floatx4 acc00 = {0,0,0,0}, acc01 = {0,0,0,0}, acc10 = {0,0,0,0}, acc11 = {0,0,0,0};
  for (int k = 0; k < S_; k += 32) {
    const s8 a0 = *(const s8*)(pA + k);
    const s8 a1 = *(const s8*)(pA + 16 * S_ + k);
    const s8 b0 = *(const s8*)(pB + k);
    const s8 b1 = *(const s8*)(pB + 16 * S_ + k);
    acc00 = __builtin_amdgcn_mfma_f32_16x16x32_bf16(a0, b0, acc00, 0, 0, 0);
    acc01 = __builtin_amdgcn_mfma_f32_16x16x32_bf16(a0, b1, acc01, 0, 0, 0);
    acc10 = __builtin_amdgcn_mfma_f32_16x16x32_bf16(a1, b0, acc10, 0, 0, 0);
    acc11 = __builtin_amdgcn_mfma_f32_16x16x32_bf16(a1, b1, acc11, 0, 0, 0);
  }
  const int crow = (lane >> 4) << 2;
  const int ccol = lane & 15;
#pragma unroll
  for (int fm = 0; fm < 2; ++fm)
#pragma unroll
    for (int r = 0; r < 4; ++r) {
      const int l = m0 + wm * 32 + fm * 16 + crow + r;
      const int lrel = (l - m0);               // row in Vb is lrel + u
      const float c = cvec[bh * L_ + l];
      const float* bap = band + (((size_t)(bh * L_ + l)) << 3);
      const float4 b0v = *(const float4*)bap;
      const float4 b1v = *(const float4*)(bap + 4);
      const float bav[7] = {b0v.x, b0v.y, b0v.z, b0v.w, b1v.x, b1v.y, b1v.z};
#pragma unroll
      for (int fn = 0; fn < 2; ++fn) {
        const floatx4 acc = (fm == 0) ? ((fn == 0) ? acc00 : acc01)
                                      : ((fn == 0) ? acc10 : acc11);
        const int d = wn * 32 + fn * 16 + ccol;
        float corr = 0.f;
#pragma unroll
        for (int u = 0; u < 7; ++u)
          corr = fmaf(bav[u], bf2f(Vb[(lrel + u) * 64 + d]), corr);
        const float val = fmaf(c, acc[r], corr);
        out1[((size_t)(b * L_ + l)) * DMODEL + h * DH + d] = f2bf(val);
      }
    }
}

// ---------------------------------------------------------------------------
extern "C" void kernel_launch(void* const* d_in, const int* in_sizes, int n_in,
                              void* d_out, int out_size, void* d_ws, size_t ws_size,
                              hipStream_t stream) {
  const float* queries = (const float*)d_in[0];
  const float* keys    = (const float*)d_in[1];
  const float* values  = (const float*)d_in[2];
  const float* Wq      = (const float*)d_in[3];
  const float* Wk      = (const float*)d_in[4];
  const float* Wv      = (const float*)d_in[5];
  const float* Wo      = (const float*)d_in[6];

  float* out  = (float*)d_out;                          // (B,L,512) f32
  float* attn = out + (size_t)B_ * L_ * DMODEL;         // (B,H,L,S) f32

  char* ws = (char*)d_ws;
  short* xbf  = (short*)(ws);                    // 12 MiB: q,k,v bf16
  short* WT   = (short*)(ws + 12u * 1048576);    //  2 MiB: 4 x W^T bf16
  short* qbf  = (short*)(ws + 14u * 1048576);    //  4 MiB (B,H,L,D)
  short* kbf  = (short*)(ws + 18u * 1048576);    //  4 MiB (B,H,S,D)  (contiguous after qbf)
  short* vT   = (short*)(ws + 22u * 1048576);    //  4 MiB (B,H,D,S)
  short* vS   = (short*)(ws + 26u * 1048576);    //  4 MiB (B,H,S,D)
  float* pm   = (float*)(ws + 30u * 1048576);    //  4 MiB (L,S) f32
  short* E    = (short*)(ws + 34u * 1048576);    //  2 MiB (L,S) bf16
  float* pmmax= (float*)(ws + 36u * 1048576);    //  4 KiB
  float* pmsum= (float*)(ws + 36u * 1048576 + 4096);        // 4 KiB
  float* cvec = (float*)(ws + 36u * 1048576 + 65536);       // 128 KiB
  float* band = (float*)(ws + 37u * 1048576);    //  1 MiB (bh,i,8) f32
  short* out1 = (short*)(ws + 38u * 1048576);    //  4 MiB (B,L,512) bf16  -> 42 MiB

  const dim3 blk(256);

  // 0) input f32->bf16, weight transpose->bf16
  hipLaunchKernelGGL(cvt_inputs_kernel, dim3(3072), blk, 0, stream,
                     queries, keys, values, xbf);
  hipLaunchKernelGGL(wtrans_kernel, dim3(16, 16, 4), blk, 0, stream,
                     Wq, Wk, Wv, Wo, WT);

  // 1) projections: q,k in one launch (grid.z=2); v dual-store
  const dim3 gProjQK(DMODEL / 64, (B_ * L_) / 64, 2);
  hipLaunchKernelGGL((proj_mfma_kernel<0>), gProjQK, blk, 0, stream,
                     xbf, WT, (void*)qbf, (short*)nullptr, DMODEL);
  const dim3 gProj(DMODEL / 64, (B_ * L_) / 64);
  hipLaunchKernelGGL((proj_mfma_kernel<3>), gProj, blk, 0, stream,
                     xbf + 4194304, WT + 524288, (void*)vT, vS, DMODEL);

  // 2) path_mean fused (no score materialization)
  hipLaunchKernelGGL(pm_fused_kernel, dim3(1024), blk, 0, stream, qbf, kbf, pm);

  // 3) per-row pm stats + E
  hipLaunchKernelGGL(pm_stats_kernel, dim3(L_ / 4), blk, 0, stream,
                     pm, E, pmmax, pmsum);

  // 4) attn rows (band recomputed from q/k), emits c + band attn
  hipLaunchKernelGGL(attn_write_kernel, dim3(L_ / 4, NBH), blk, 0, stream,
                     attn, E, pmmax, pmsum, qbf, kbf, cvec, band);

  // 5) EV GEMM + band correction -> out1 bf16
  hipLaunchKernelGGL(ev_kernel, dim3(L_ / 64, NBH), blk, 0, stream,
                     E, vT, vS, cvec, band, out1);

  // 6) out = out1 @ W_o (MFMA, f32 out)
  hipLaunchKernelGGL((proj_mfma_kernel<2>), gProj, blk, 0, stream,
                     out1, WT + 786432, (void*)out, (short*)nullptr, DMODEL);
}

// Round 7
// 201.871 us; speedup vs baseline: 1.1250x; 1.1250x over previous
//
#include <hip/hip_runtime.h>
#include <math.h>

static constexpr int B_ = 4;
static constexpr int L_ = 1024;
static constexpr int S_ = 1024;
static constexpr int DMODEL = 512;
static constexpr int NH = 8;
static constexpr int DH = 64;
static constexpr int NBH = 32;   // B_*NH

typedef __attribute__((ext_vector_type(8))) short s8;      // 8 bf16 (4 VGPRs)
typedef __attribute__((ext_vector_type(4))) float floatx4; // MFMA accumulator

__device__ __forceinline__ short f2bf(float f) {           // RNE f32->bf16
  unsigned u = __float_as_uint(f);
  return (short)((u + 0x7fffu + ((u >> 16) & 1u)) >> 16);
}
__device__ __forceinline__ float bf2f(short s) {
  return __uint_as_float(((unsigned)(unsigned short)s) << 16);
}

// ---------------------------------------------------------------------------
// Convert q/k/v (f32) -> contiguous bf16 segments; also init bandS to -1e30.
// ---------------------------------------------------------------------------
__global__ __launch_bounds__(256)
void cvt_inputs_kernel(const float* __restrict__ q, const float* __restrict__ k,
                       const float* __restrict__ v, short* __restrict__ dst,
                       float* __restrict__ bandS) {
  const int i = blockIdx.x * 256 + threadIdx.x;          // 0..786431
  if (i < 32768) {                                       // bandS: 32*1024*8 f32
    const float4 m4 = make_float4(-1e30f, -1e30f, -1e30f, -1e30f);
    *(float4*)(bandS + ((size_t)i << 3)) = m4;
    *(float4*)(bandS + ((size_t)i << 3) + 4) = m4;
  }
  const int arr = i >> 18;                               // 0..2 (uniform per block)
  const int off = (i & 262143) << 3;
  const float* src = (arr == 0) ? q : (arr == 1) ? k : v;
  const float4 f0 = *(const float4*)(src + off);
  const float4 f1 = *(const float4*)(src + off + 4);
  s8 o;
  o[0] = f2bf(f0.x); o[1] = f2bf(f0.y); o[2] = f2bf(f0.z); o[3] = f2bf(f0.w);
  o[4] = f2bf(f1.x); o[5] = f2bf(f1.y); o[6] = f2bf(f1.z); o[7] = f2bf(f1.w);
  *(s8*)(dst + (size_t)arr * 2097152 + off) = o;
}

// ---------------------------------------------------------------------------
// Transpose + cvt the 4 weight matrices: W (512x512 f32, [k][n]) -> WT bf16 [n][k]
// ---------------------------------------------------------------------------
__global__ __launch_bounds__(256)
void wtrans_kernel(const float* __restrict__ Wq, const float* __restrict__ Wk,
                   const float* __restrict__ Wv, const float* __restrict__ Wo,
                   short* __restrict__ WT) {
  __shared__ float t[32][33];
  const int z = blockIdx.z;
  const float* W = (z == 0) ? Wq : (z == 1) ? Wk : (z == 2) ? Wv : Wo;
  short* dst = WT + (size_t)z * 262144;
  const int k0 = blockIdx.y * 32, n0 = blockIdx.x * 32;
  const int row = threadIdx.x >> 3;          // 0..31
  const int c4 = (threadIdx.x & 7) << 2;     // 0,4,..28
  const float4 f = *(const float4*)(W + (size_t)(k0 + row) * 512 + n0 + c4);
  t[row][c4 + 0] = f.x; t[row][c4 + 1] = f.y; t[row][c4 + 2] = f.z; t[row][c4 + 3] = f.w;
  __syncthreads();
#pragma unroll
  for (int j = 0; j < 4; ++j)
    dst[(size_t)(n0 + row) * 512 + k0 + c4 + j] = f2bf(t[c4 + j][row]);
}

// ---------------------------------------------------------------------------
// q/k/v projections in one launch. z=0: q->(B,H,L,D); z=1: k->(B,H,S,D);
// z=2: v dual-store vT (B,H,D,S) + vS (B,H,S,D).
// ---------------------------------------------------------------------------
__global__ __launch_bounds__(256)
void proj_qkv_kernel(const short* __restrict__ xbf, const short* __restrict__ WTall,
                     short* __restrict__ qk, short* __restrict__ vT,
                     short* __restrict__ vS) {
  const int z = blockIdx.z;
  const short* A = xbf + (size_t)z * 2097152;
  const short* WT = WTall + (size_t)z * 262144;
  const int K = DMODEL;
  const int tid = threadIdx.x;
  const int lane = tid & 63, w = tid >> 6;
  const int wm = w >> 1, wn = w & 1;
  const int m0 = blockIdx.y * 64, n0 = blockIdx.x * 64;
  const int kl = (lane >> 4) << 3;
  const short* pA = A + (size_t)(m0 + wm * 32 + (lane & 15)) * K + kl;
  const short* pB = WT + (size_t)(n0 + wn * 32 + (lane & 15)) * K + kl;
  const size_t f16K = (size_t)16 * K;
  floatx4 acc00 = {0,0,0,0}, acc01 = {0,0,0,0}, acc10 = {0,0,0,0}, acc11 = {0,0,0,0};
  for (int k = 0; k < K; k += 32) {
    const s8 a0 = *(const s8*)(pA + k);
    const s8 a1 = *(const s8*)(pA + f16K + k);
    const s8 b0 = *(const s8*)(pB + k);
    const s8 b1 = *(const s8*)(pB + f16K + k);
    acc00 = __builtin_amdgcn_mfma_f32_16x16x32_bf16(a0, b0, acc00, 0, 0, 0);
    acc01 = __builtin_amdgcn_mfma_f32_16x16x32_bf16(a0, b1, acc01, 0, 0, 0);
    acc10 = __builtin_amdgcn_mfma_f32_16x16x32_bf16(a1, b0, acc10, 0, 0, 0);
    acc11 = __builtin_amdgcn_mfma_f32_16x16x32_bf16(a1, b1, acc11, 0, 0, 0);
  }
  const int crow = (lane >> 4) << 2;
  const int ccol = lane & 15;
#pragma unroll
  for (int fm = 0; fm < 2; ++fm)
#pragma unroll
    for (int fn = 0; fn < 2; ++fn) {
      const floatx4 acc = (fm == 0) ? ((fn == 0) ? acc00 : acc01)
                                    : ((fn == 0) ? acc10 : acc11);
      const int col = n0 + wn * 32 + fn * 16 + ccol;
#pragma unroll
      for (int r = 0; r < 4; ++r) {
        const int row = m0 + wm * 32 + fm * 16 + crow + r;
        const int b = row >> 10, l = row & 1023, h = col >> 6, d = col & 63;
        const short val = f2bf(acc[r]);
        if (z < 2) {
          qk[(size_t)z * 2097152 + ((size_t)((b * NH + h) * L_ + l)) * DH + d] = val;
        } else {
          vT[((size_t)((b * NH + h) * DH + d)) * S_ + l] = val;   // l==s here
          vS[((size_t)((b * NH + h) * S_ + l)) * DH + d] = val;
        }
      }
    }
}

// ---------------------------------------------------------------------------
// Scores in bf16: Sbf[bh][l][s] = bf16(0.125 * q.k); band (|l-s|<=3) also
// stored as f32 (pre-rounding) into bandS[bh][l][8] for exact softmax later.
// ---------------------------------------------------------------------------
__global__ __launch_bounds__(256)
void scores_bf16_kernel(const short* __restrict__ qbf, const short* __restrict__ kbf,
                        short* __restrict__ Sbf, float* __restrict__ bandS) {
  const int tid = threadIdx.x;
  const int lane = tid & 63, w = tid >> 6;
  const int wm = w >> 1, wn = w & 1;
  const int m0 = blockIdx.y * 64, n0 = blockIdx.x * 64;
  const int bh = blockIdx.z;
  const int kl = (lane >> 4) << 3;
  const short* pA = qbf + (size_t)bh * L_ * DH + (size_t)(m0 + wm * 32 + (lane & 15)) * DH + kl;
  const short* pB = kbf + (size_t)bh * S_ * DH + (size_t)(n0 + wn * 32 + (lane & 15)) * DH + kl;
  floatx4 acc00 = {0,0,0,0}, acc01 = {0,0,0,0}, acc10 = {0,0,0,0}, acc11 = {0,0,0,0};
#pragma unroll
  for (int k = 0; k < DH; k += 32) {
    const s8 a0 = *(const s8*)(pA + k);
    const s8 a1 = *(const s8*)(pA + 16 * DH + k);
    const s8 b0 = *(const s8*)(pB + k);
    const s8 b1 = *(const s8*)(pB + 16 * DH + k);
    acc00 = __builtin_amdgcn_mfma_f32_16x16x32_bf16(a0, b0, acc00, 0, 0, 0);
    acc01 = __builtin_amdgcn_mfma_f32_16x16x32_bf16(a0, b1, acc01, 0, 0, 0);
    acc10 = __builtin_amdgcn_mfma_f32_16x16x32_bf16(a1, b0, acc10, 0, 0, 0);
    acc11 = __builtin_amdgcn_mfma_f32_16x16x32_bf16(a1, b1, acc11, 0, 0, 0);
  }
  short* Sp = Sbf + ((size_t)bh << 20);
  const int crow = (lane >> 4) << 2;
  const int ccol = lane & 15;
#pragma unroll
  for (int fm = 0; fm < 2; ++fm)
#pragma unroll
    for (int fn = 0; fn < 2; ++fn) {
      const floatx4 acc = (fm == 0) ? ((fn == 0) ? acc00 : acc01)
                                    : ((fn == 0) ? acc10 : acc11);
      const int col = n0 + wn * 32 + fn * 16 + ccol;
#pragma unroll
      for (int r = 0; r < 4; ++r) {
        const int row = m0 + wm * 32 + fm * 16 + crow + r;
        const float sc = acc[r] * 0.125f;
        Sp[(size_t)row * S_ + col] = f2bf(sc);
        const int dd = col - row;
        if (dd >= -3 && dd <= 3)
          bandS[(((size_t)bh << 10) + row) * 8 + dd + 3] = sc;
      }
    }
}

// ---------------------------------------------------------------------------
// path_mean from bf16 scores (tiled gather through LDS, staged as f32).
//   pm[i][j] = (1/32) sum_bh Sc[bh][i][m1] * Sc[bh][m2][j]
// ---------------------------------------------------------------------------
__global__ __launch_bounds__(256)
void path_mean_kernel(const short* __restrict__ Sbf, float* __restrict__ pm) {
  __shared__ float As[32][44];   // rows i0.., cols c0a..c0a+39 (c0a = c0&~7)
  __shared__ float Bs[32][36];   // rows r0.., cols j0..j0+31
  const int orig = blockIdx.x;
  const int wgid = (orig & 7) * 128 + (orig >> 3);     // bijective XCD swizzle
  const int i0 = (wgid >> 5) << 5;
  const int j0 = (wgid & 31) << 5;
  const int c0 = (2 * i0 + j0) / 3;
  const int c0a = c0 & ~7;
  const int r0 = (i0 + 2 * j0) / 3;
  const int tid = threadIdx.x;
  const int ti = tid >> 3;           // 0..31 output row
  const int tj = tid & 7;            // 0..7  output col quad
  const int gi = i0 + ti;
  int aoff[4], boff[4];
#pragma unroll
  for (int b = 0; b < 4; ++b) {
    const int gj = j0 + 4 * tj + b;
    const int m1 = (2 * gi + gj) / 3;
    const int m2 = (gi + 2 * gj) / 3;
    aoff[b] = ti * 44 + (m1 - c0a);
    boff[b] = (m2 - r0) * 36 + (4 * tj + b);
  }
  // staging units: A = 32 rows x 5 chunks(8 bf16) = 160; B = 32 x 4 = 128
  const int uA = tid;                   // <160 -> A unit, 160..255 -> B unit
  const int uB2 = tid + 256;            // tid<32 -> B unit 96..127
  int arow = 0, ac = 0, brow = 0, bc = 0, brow2 = 0, bc2 = 0;
  bool isA = uA < 160;
  if (isA) { arow = uA / 5; ac = uA - arow * 5; }
  else { const int v = uA - 160; brow = v >> 2; bc = v & 3; }
  const bool hasU2 = tid < 32;
  { const int v = uB2 - 160; brow2 = v >> 2; bc2 = v & 3; }
  int gcA = c0a + (ac << 3); if (gcA > 1016) gcA = 1016;
  const short* pA = Sbf + (size_t)(i0 + arow) * S_ + gcA;
  const short* pB = Sbf + (size_t)(r0 + brow) * S_ + j0 + (bc << 3);
  const short* pB2 = Sbf + (size_t)(r0 + brow2) * S_ + j0 + (bc2 << 3);

  const float* As0 = &As[0][0];
  const float* Bs0 = &Bs[0][0];
  float acc[4] = {0.f, 0.f, 0.f, 0.f};
  for (int z = 0; z < NBH; ++z) {
    const size_t zo = (size_t)z << 20;
    const s8 v1 = isA ? *(const s8*)(pA + zo) : *(const s8*)(pB + zo);
    s8 v2;
    if (hasU2) v2 = *(const s8*)(pB2 + zo);
    __syncthreads();                  // previous iteration's gathers done
    {
      float4 lo, hi;
      lo.x = bf2f(v1[0]); lo.y = bf2f(v1[1]); lo.z = bf2f(v1[2]); lo.w = bf2f(v1[3]);
      hi.x = bf2f(v1[4]); hi.y = bf2f(v1[5]); hi.z = bf2f(v1[6]); hi.w = bf2f(v1[7]);
      if (isA) {
        *(float4*)&As[arow][ac << 3] = lo;
        *(float4*)&As[arow][(ac << 3) + 4] = hi;
      } else {
        *(float4*)&Bs[brow][bc << 3] = lo;
        *(float4*)&Bs[brow][(bc << 3) + 4] = hi;
      }
      if (hasU2) {
        float4 lo2, hi2;
        lo2.x = bf2f(v2[0]); lo2.y = bf2f(v2[1]); lo2.z = bf2f(v2[2]); lo2.w = bf2f(v2[3]);
        hi2.x = bf2f(v2[4]); hi2.y = bf2f(v2[5]); hi2.z = bf2f(v2[6]); hi2.w = bf2f(v2[7]);
        *(float4*)&Bs[brow2][bc2 << 3] = lo2;
        *(float4*)&Bs[brow2][(bc2 << 3) + 4] = hi2;
      }
    }
    __syncthreads();
#pragma unroll
    for (int b = 0; b < 4; ++b)
      acc[b] = fmaf(As0[aoff[b]], Bs0[boff[b]], acc[b]);
  }
  float4 o = make_float4(acc[0] * (1.f / 32.f), acc[1] * (1.f / 32.f),
                         acc[2] * (1.f / 32.f), acc[3] * (1.f / 32.f));
  *(float4*)&pm[(size_t)gi * S_ + j0 + 4 * tj] = o;
}

// ---------------------------------------------------------------------------
// pm_stats: per row i (far positions only): pmmax, pmsum, E=bf16(exp(pm-max))
// ---------------------------------------------------------------------------
__global__ __launch_bounds__(256)
void pm_stats_kernel(const float* __restrict__ pm, short* __restrict__ E,
                     float* __restrict__ pmmax, float* __restrict__ pmsum) {
  const int wid = threadIdx.x >> 6, lane = threadIdx.x & 63;
  const int i = blockIdx.x * 4 + wid;
  const float* row = pm + (size_t)i * S_;
  const int j0 = lane << 4;
  float v[16];
#pragma unroll
  for (int c = 0; c < 4; ++c) {
    const float4 f = *(const float4*)(row + j0 + c * 4);
    v[c * 4 + 0] = f.x; v[c * 4 + 1] = f.y; v[c * 4 + 2] = f.z; v[c * 4 + 3] = f.w;
  }
  float mx = -1e30f;
#pragma unroll
  for (int u = 0; u < 16; ++u) {
    const int d = i - (j0 + u);
    const bool far = (d > 3) || (d < -3);
    if (far) mx = fmaxf(mx, v[u]);
  }
#pragma unroll
  for (int off = 32; off >= 1; off >>= 1) mx = fmaxf(mx, __shfl_xor(mx, off));
  float sum = 0.f;
  short e[16];
#pragma unroll
  for (int u = 0; u < 16; ++u) {
    const int d = i - (j0 + u);
    const bool far = (d > 3) || (d < -3);
    const float ev = far ? __expf(v[u] - mx) : 0.f;
    sum += ev;
    e[u] = f2bf(ev);
  }
#pragma unroll
  for (int off = 32; off >= 1; off >>= 1) sum += __shfl_xor(sum, off);
  s8 o0, o1;
#pragma unroll
  for (int u = 0; u < 8; ++u) { o0[u] = e[u]; o1[u] = e[8 + u]; }
  short* Erow = E + (size_t)i * S_ + j0;
  *(s8*)Erow = o0;
  *(s8*)(Erow + 8) = o1;
  if (lane == 0) { pmmax[i] = mx; pmsum[i] = sum; }
}

// ---------------------------------------------------------------------------
// ev_fused: per (64-row tile, bh):
//   stage 1: c[l], bandAttn[l][7] from bandS + pmmax/pmsum (exact f32 band)
//   stage 2: MFMA E@V; the A-fragments stream every E element of the tile's
//            attn rows -> write attn = c*E (band-patched) inline.
//   stage 3: out1 = c*acc + sum_band bandAttn*V (V band rows in LDS).
// ---------------------------------------------------------------------------
__global__ __launch_bounds__(256)
void ev_fused_kernel(const short* __restrict__ E, const short* __restrict__ vT,
                     const short* __restrict__ vS, const float* __restrict__ bandS,
                     const float* __restrict__ pmmax, const float* __restrict__ pmsum,
                     float* __restrict__ attn, short* __restrict__ out1) {
  __shared__ float cL[64];
  __shared__ float bL[64][8];
  __shared__ short Vb[70 * 64];
  const int tid = threadIdx.x;
  const int m0 = blockIdx.x * 64;
  const int bh = blockIdx.y;
  const int b = bh >> 3, h = bh & 7;

  // stage V band rows (m0-3 .. m0+66, clamped)
  for (int idx = tid; idx < 560; idx += 256) {
    const int rr = idx >> 3, c8 = (idx & 7) << 3;
    int j = m0 - 3 + rr; j = j < 0 ? 0 : (j > 1023 ? 1023 : j);
    *(s8*)&Vb[rr * 64 + c8] = *(const s8*)(vS + ((size_t)bh * S_ + j) * DH + c8);
  }

  // stage 1: softmax combine (4 threads per row)
  {
    const int r = tid >> 2, p = tid & 3;
    const int l = m0 + r;
    const float pmx = pmmax[l], psum = pmsum[l];
    const float* bs = bandS + (((size_t)bh << 10) + l) * 8;
    const float sa = bs[p], sb2 = bs[p + 4];          // slot 7 = -1e30 (init)
    float mx = fmaxf(sa, sb2);
    mx = fmaxf(mx, __shfl_xor(mx, 1));
    mx = fmaxf(mx, __shfl_xor(mx, 2));
    const float m = fmaxf(mx, pmx);
    const float ea = __expf(sa - m), eb = __expf(sb2 - m);
    float bsum = ea + eb;
    bsum += __shfl_xor(bsum, 1);
    bsum += __shfl_xor(bsum, 2);
    const float cpm = __expf(pmx - m);
    const float inv = 1.f / (bsum + psum * cpm);
    if (p == 0) cL[r] = cpm * inv;
    bL[r][p] = ea * inv;
    bL[r][p + 4] = eb * inv;
  }
  __syncthreads();

  const int lane = tid & 63, w = tid >> 6;
  const int wm = w >> 1, wn = w & 1;
  const int frow = lane & 15;
  const int kl = (lane >> 4) << 3;
  const int ra0 = m0 + wm * 32 + frow;               // a0 row; a1 row = ra0+16
  const int lr0 = wm * 32 + frow;                    // tile-relative rows
  const int lr1 = lr0 + 16;
  const short* pA = E + (size_t)ra0 * S_ + kl;
  const short* pB = vT + (size_t)bh * DH * S_ + (size_t)(wn * 32 + frow) * S_ + kl;
  const float c0v = cL[lr0];
  const float c1v = cL[lr1];
  float* arow0 = attn + ((size_t)bh * L_ + ra0) * S_;
  float* arow1 = arow0 + (size_t)16 * S_;
  floatx4 acc00 = {0,0,0,0}, acc01 = {0,0,0,0}, acc10 = {0,0,0,0}, acc11 = {0,0,0,0};
  for (int k = 0; k < S_; k += 32) {
    const s8 a0 = *(const s8*)(pA + k);
    const s8 a1 = *(const s8*)(pA + 16 * S_ + k);
    const s8 b0 = *(const s8*)(pB + k);
    const s8 b1 = *(const s8*)(pB + 16 * S_ + k);
    acc00 = __builtin_amdgcn_mfma_f32_16x16x32_bf16(a0, b0, acc00, 0, 0, 0);
    acc01 = __builtin_amdgcn_mfma_f32_16x16x32_bf16(a0, b1, acc01, 0, 0, 0);
    acc10 = __builtin_amdgcn_mfma_f32_16x16x32_bf16(a1, b0, acc10, 0, 0, 0);
    acc11 = __builtin_amdgcn_mfma_f32_16x16x32_bf16(a1, b1, acc11, 0, 0, 0);
    const int jw = k + kl;
    if (wn == 0) {                                   // this wave writes a0 rows
      float att[8];
#pragma unroll
      for (int e = 0; e < 8; ++e) att[e] = bf2f(a0[e]) * c0v;
      const int rel = ra0 - jw;                      // band cols: e in [rel-3, rel+3]
      if ((unsigned)(rel + 3) <= 13u) {
#pragma unroll
        for (int e = 0; e < 8; ++e) {
          const int d = e - rel;
          if ((unsigned)(d + 3) <= 6u) att[e] = bL[lr0][d + 3];
        }
      }
      *(float4*)(arow0 + jw) = make_float4(att[0], att[1], att[2], att[3]);
      *(float4*)(arow0 + jw + 4) = make_float4(att[4], att[5], att[6], att[7]);
    } else {                                         // this wave writes a1 rows
      float att[8];
#pragma unroll
      for (int e = 0; e < 8; ++e) att[e] = bf2f(a1[e]) * c1v;
      const int rel = ra0 + 16 - jw;
      if ((unsigned)(rel + 3) <= 13u) {
#pragma unroll
        for (int e = 0; e < 8; ++e) {
          const int d = e - rel;
          if ((unsigned)(d + 3) <= 6u) att[e] = bL[lr1][d + 3];
        }
      }
      *(float4*)(arow1 + jw) = make_float4(att[0], att[1], att[2], att[3]);
      *(float4*)(arow1 + jw + 4) = make_float4(att[4], att[5], att[6], att[7]);
    }
  }

  const int crow = (lane >> 4) << 2;
  const int ccol = lane & 15;
#pragma unroll
  for (int fm = 0; fm < 2; ++fm)
#pragma unroll
    for (int r = 0; r < 4; ++r) {
      const int lrel = wm * 32 + fm * 16 + crow + r;  // l - m0
      const int l = m0 + lrel;
      const float cc = cL[lrel];
      const float4 b0v = *(const float4*)&bL[lrel][0];
      const float4 b1v = *(const float4*)&bL[lrel][4];
      const float bav[7] = {b0v.x, b0v.y, b0v.z, b0v.w, b1v.x, b1v.y, b1v.z};
#pragma unroll
      for (int fn = 0; fn < 2; ++fn) {
        const floatx4 acc = (fm == 0) ? ((fn == 0) ? acc00 : acc01)
                                      : ((fn == 0) ? acc10 : acc11);
        const int d = wn * 32 + fn * 16 + ccol;
        float corr = 0.f;
#pragma unroll
        for (int u = 0; u < 7; ++u)
          corr = fmaf(bav[u], bf2f(Vb[(lrel + u) * 64 + d]), corr);
        const float val = fmaf(cc, acc[r], corr);
        out1[((size_t)(b * L_ + l)) * DMODEL + h * DH + d] = f2bf(val);
      }
    }
}

// ---------------------------------------------------------------------------
// Output projection: out(f32) = out1(bf16) @ Wo^T
// ---------------------------------------------------------------------------
__global__ __launch_bounds__(256)
void proj_out_kernel(const short* __restrict__ A, const short* __restrict__ WT,
                     float* __restrict__ C) {
  const int K = DMODEL;
  const int tid = threadIdx.x;
  const int lane = tid & 63, w = tid >> 6;
  const int wm = w >> 1, wn = w & 1;
  const int m0 = blockIdx.y * 64, n0 = blockIdx.x * 64;
  const int kl = (lane >> 4) << 3;
  const short* pA = A + (size_t)(m0 + wm * 32 + (lane & 15)) * K + kl;
  const short* pB = WT + (size_t)(n0 + wn * 32 + (lane & 15)) * K + kl;
  const size_t f16K = (size_t)16 * K;
  floatx4 acc00 = {0,0,0,0}, acc01 = {0,0,0,0}, acc10 = {0,0,0,0}, acc11 = {0,0,0,0};
  for (int k = 0; k < K; k += 32) {
    const s8 a0 = *(const s8*)(pA + k);
    const s8 a1 = *(const s8*)(pA + f16K + k);
    const s8 b0 = *(const s8*)(pB + k);
    const s8 b1 = *(const s8*)(pB + f16K + k);
    acc00 = __builtin_amdgcn_mfma_f32_16x16x32_bf16(a0, b0, acc00, 0, 0, 0);
    acc01 = __builtin_amdgcn_mfma_f32_16x16x32_bf16(a0, b1, acc01, 0, 0, 0);
    acc10 = __builtin_amdgcn_mfma_f32_16x16x32_bf16(a1, b0, acc10, 0, 0, 0);
    acc11 = __builtin_amdgcn_mfma_f32_16x16x32_bf16(a1, b1, acc11, 0, 0, 0);
  }
  const int crow = (lane >> 4) << 2;
  const int ccol = lane & 15;
#pragma unroll
  for (int fm = 0; fm < 2; ++fm)
#pragma unroll
    for (int fn = 0; fn < 2; ++fn) {
      const floatx4 acc = (fm == 0) ? ((fn == 0) ? acc00 : acc01)
                                    : ((fn == 0) ? acc10 : acc11);
      const int col = n0 + wn * 32 + fn * 16 + ccol;
#pragma unroll
      for (int r = 0; r < 4; ++r) {
        const int row = m0 + wm * 32 + fm * 16 + crow + r;
        C[(size_t)row * DMODEL + col] = acc[r];
      }
    }
}

// ---------------------------------------------------------------------------
extern "C" void kernel_launch(void* const* d_in, const int* in_sizes, int n_in,
                              void* d_out, int out_size, void* d_ws, size_t ws_size,
                              hipStream_t stream) {
  const float* queries = (const float*)d_in[0];
  const float* keys    = (const float*)d_in[1];
  const float* values  = (const float*)d_in[2];
  const float* Wq      = (const float*)d_in[3];
  const float* Wk      = (const float*)d_in[4];
  const float* Wv      = (const float*)d_in[5];
  const float* Wo      = (const float*)d_in[6];

  float* out  = (float*)d_out;                          // (B,L,512) f32
  float* attn = out + (size_t)B_ * L_ * DMODEL;         // (B,H,L,S) f32

  char* ws = (char*)d_ws;
  short* xbf   = (short*)(ws);                    // 12 MiB: q,k,v bf16
  short* WT    = (short*)(ws + 12u * 1048576);    //  2 MiB: 4 x W^T bf16
  short* qkbf  = (short*)(ws + 14u * 1048576);    //  8 MiB: qbf + kbf
  short* vT    = (short*)(ws + 22u * 1048576);    //  4 MiB (B,H,D,S)
  short* vS    = (short*)(ws + 26u * 1048576);    //  4 MiB (B,H,S,D)
  float* pm    = (float*)(ws + 30u * 1048576);    //  4 MiB (L,S) f32
  short* E     = (short*)(ws + 34u * 1048576);    //  2 MiB (L,S) bf16
  float* pmmax = (float*)(ws + 36u * 1048576);    //  4 KiB
  float* pmsum = (float*)(ws + 36u * 1048576 + 4096);       // 4 KiB
  float* bandS = (float*)(ws + 37u * 1048576);    //  1 MiB (bh,l,8) f32
  short* out1  = (short*)(ws + 38u * 1048576);    //  4 MiB (B,L,512) bf16
  short* Sbf   = (short*)(ws + 42u * 1048576);    // 64 MiB (bh,L,S) bf16 -> 106 MiB

  const dim3 blk(256);

  // 0) cvt inputs + bandS init; weight transpose
  hipLaunchKernelGGL(cvt_inputs_kernel, dim3(3072), blk, 0, stream,
                     queries, keys, values, xbf, bandS);
  hipLaunchKernelGGL(wtrans_kernel, dim3(16, 16, 4), blk, 0, stream,
                     Wq, Wk, Wv, Wo, WT);

  // 1) q/k/v projections, one launch
  hipLaunchKernelGGL(proj_qkv_kernel, dim3(DMODEL / 64, (B_ * L_) / 64, 3),
                     blk, 0, stream, xbf, WT, qkbf, vT, vS);

  // 2) scores bf16 + exact band extraction
  hipLaunchKernelGGL(scores_bf16_kernel, dim3(S_ / 64, L_ / 64, NBH), blk, 0, stream,
                     qkbf, qkbf + 2097152, Sbf, bandS);

  // 3) path_mean (tiled gather over bf16 scores)
  hipLaunchKernelGGL(path_mean_kernel, dim3(1024), blk, 0, stream, Sbf, pm);

  // 4) pm stats + E
  hipLaunchKernelGGL(pm_stats_kernel, dim3(L_ / 4), blk, 0, stream,
                     pm, E, pmmax, pmsum);

  // 5) EV GEMM with fused attn write + band epilogue
  hipLaunchKernelGGL(ev_fused_kernel, dim3(L_ / 64, NBH), blk, 0, stream,
                     E, vT, vS, bandS, pmmax, pmsum, attn, out1);

  // 6) out = out1 @ W_o
  hipLaunchKernelGGL(proj_out_kernel, dim3(DMODEL / 64, (B_ * L_) / 64), blk, 0, stream,
                     out1, WT + 786432, out);
}